// Round 7
// baseline (240.161 us; speedup 1.0000x reference)
//
#include <hip/hip_runtime.h>
#include <stdint.h>

#define NN 100000
#define NE 1600000
#define DD 128
#define NTILES ((NN + 127) / 128)   // 782
#define NB 256                      // phase-A blocks
#define CHUNK (NE / NB)             // 6250
#define NBUCK ((NN + 255) / 256)    // 391 coarse buckets (dst>>8)
#define GH_N (NBUCK * NB)           // 100,096
#define GH_BLK (GH_N / 256)         // 391 scan blocks (exact)

typedef __bf16 bf16x8 __attribute__((ext_vector_type(8)));
typedef float f32x4 __attribute__((ext_vector_type(4)));
typedef float f32x2 __attribute__((ext_vector_type(2)));

// round-to-nearest-even fp32 -> bf16, two at a time, packed into a uint
__device__ __forceinline__ unsigned int f2bf2(float a, float b) {
  union { float f; unsigned u; } x, y;
  x.f = a; y.f = b;
  unsigned ua = x.u + (0x7FFFu + ((x.u >> 16) & 1u));
  unsigned ub = y.u + (0x7FFFu + ((y.u >> 16) & 1u));
  return (ua >> 16) | (ub & 0xFFFF0000u);
}

// ---------------- 0. h (fp32) -> h8 (fp8 e4m3), 8 elems/thread --------------
__global__ __launch_bounds__(256) void convert_h8_kernel(const float4* __restrict__ hp,
                                                         uint2* __restrict__ h8) {
  int gid = blockIdx.x * 256 + threadIdx.x;   // NN*DD/8 = 1.6M threads
  float4 a = hp[2 * gid], b = hp[2 * gid + 1];
  int lo = __builtin_amdgcn_cvt_pk_fp8_f32(a.x, a.y, 0, false);
  lo = __builtin_amdgcn_cvt_pk_fp8_f32(a.z, a.w, lo, true);
  int hi = __builtin_amdgcn_cvt_pk_fp8_f32(b.x, b.y, 0, false);
  hi = __builtin_amdgcn_cvt_pk_fp8_f32(b.z, b.w, hi, true);
  h8[gid] = make_uint2((unsigned)lo, (unsigned)hi);
}

// ---------------- A1. coarse histogram (LDS atomics only) -------------------
__global__ __launch_bounds__(256) void coarse_hist_kernel(const int* __restrict__ dst,
                                                          int* __restrict__ gh) {
  __shared__ int lh[NBUCK];
  int t = threadIdx.x, b = blockIdx.x;
  for (int i = t; i < NBUCK; i += 256) lh[i] = 0;
  __syncthreads();
  int e0 = b * CHUNK;
  for (int e = e0 + t; e < e0 + CHUNK; e += 256)
    atomicAdd(&lh[dst[e] >> 8], 1);
  __syncthreads();
  for (int i = t; i < NBUCK; i += 256) gh[i * NB + b] = lh[i];
}

// ---------------- A2. hierarchical exclusive scan of gh ---------------------
__global__ __launch_bounds__(256) void blocksum_kernel(const int* __restrict__ gh,
                                                       int* __restrict__ bsum) {
  __shared__ int s[256];
  int t = threadIdx.x;
  s[t] = gh[blockIdx.x * 256 + t];
  __syncthreads();
  for (int d = 128; d > 0; d >>= 1) {
    if (t < d) s[t] += s[t + d];
    __syncthreads();
  }
  if (t == 0) bsum[blockIdx.x] = s[0];
}

__global__ __launch_bounds__(512) void scanbsum_kernel(const int* __restrict__ bsum,
                                                       int* __restrict__ bsum_ex) {
  __shared__ int s[512];
  int t = threadIdx.x;
  int v = (t < GH_BLK) ? bsum[t] : 0;
  s[t] = v;
  __syncthreads();
  for (int d = 1; d < 512; d <<= 1) {
    int x = (t >= d) ? s[t - d] : 0;
    __syncthreads();
    s[t] += x;
    __syncthreads();
  }
  if (t < GH_BLK) bsum_ex[t] = s[t] - v;
}

__global__ __launch_bounds__(256) void scanfull_kernel(const int* __restrict__ gh,
                                                       const int* __restrict__ bsum_ex,
                                                       int* __restrict__ gsc) {
  __shared__ int s[256];
  int t = threadIdx.x;
  int idx = blockIdx.x * 256 + t;
  int v = gh[idx];
  s[t] = v;
  __syncthreads();
  for (int d = 1; d < 256; d <<= 1) {
    int x = (t >= d) ? s[t - d] : 0;
    __syncthreads();
    s[t] += x;
    __syncthreads();
  }
  gsc[idx] = bsum_ex[blockIdx.x] + s[t] - v;
}

// ---------------- A3. coarse scatter, LDS-staged burst writeback ------------
__global__ __launch_bounds__(256) void coarse_scatter_kernel(
    const int* __restrict__ src, const int* __restrict__ dst,
    const int* __restrict__ gsc, unsigned* __restrict__ ebuf) {
  __shared__ int lhpad[512];
  __shared__ int lbase[NBUCK];
  __shared__ int lcur[NBUCK];
  __shared__ int gstart[NBUCK];
  __shared__ unsigned sdata[CHUNK];
  __shared__ int sgpos[CHUNK];
  int t = threadIdx.x, b = blockIdx.x;
  lhpad[t] = 0;
  lhpad[t + 256] = 0;
  __syncthreads();
  int e0 = b * CHUNK;
  for (int e = e0 + t; e < e0 + CHUNK; e += 256)
    atomicAdd(&lhpad[dst[e] >> 8], 1);
  __syncthreads();
  int cnt0 = lhpad[t], cnt1 = lhpad[t + 256];
  for (int d = 1; d < 512; d <<= 1) {
    int x0 = (t >= d) ? lhpad[t - d] : 0;
    int x1 = ((t + 256) >= d) ? lhpad[t + 256 - d] : 0;
    __syncthreads();
    lhpad[t] += x0;
    lhpad[t + 256] += x1;
    __syncthreads();
  }
  if (t < NBUCK) { lbase[t] = lhpad[t] - cnt0; lcur[t] = 0; gstart[t] = gsc[t * NB + b]; }
  int i2 = t + 256;
  if (i2 < NBUCK) { lbase[i2] = lhpad[i2] - cnt1; lcur[i2] = 0; gstart[i2] = gsc[i2 * NB + b]; }
  __syncthreads();
  for (int e = e0 + t; e < e0 + CHUNK; e += 256) {
    int d = dst[e], s = src[e];
    int bk = d >> 8;
    int slot = atomicAdd(&lcur[bk], 1);
    int lp = lbase[bk] + slot;
    sdata[lp] = ((unsigned)(d & 255) << 24) | (unsigned)s;
    sgpos[lp] = gstart[bk] + slot;
  }
  __syncthreads();
  for (int j = t; j < CHUNK; j += 256) ebuf[sgpos[j]] = sdata[j];
}

// ---------------- B. fine sort within bucket -> csr + offs ------------------
__global__ __launch_bounds__(256) void fine_sort_kernel(const unsigned* __restrict__ ebuf,
                                                        const int* __restrict__ gsc,
                                                        int* __restrict__ csr,
                                                        int* __restrict__ offs) {
  __shared__ int hist[256], scn[256], cur[256];
  int t = threadIdx.x, g = blockIdx.x;
  int base = gsc[g * NB];
  int end = (g == NBUCK - 1) ? NE : gsc[(g + 1) * NB];
  hist[t] = 0;
  __syncthreads();
  for (int j = base + t; j < end; j += 256)
    atomicAdd(&hist[ebuf[j] >> 24], 1);
  __syncthreads();
  int v = hist[t];
  scn[t] = v;
  __syncthreads();
  for (int d = 1; d < 256; d <<= 1) {
    int x = (t >= d) ? scn[t - d] : 0;
    __syncthreads();
    scn[t] += x;
    __syncthreads();
  }
  int excl = scn[t] - v;
  int node = g * 256 + t;
  if (node < NN) offs[node] = base + excl;
  if (node == NN - 1) offs[NN] = NE;
  cur[t] = excl;
  __syncthreads();
  for (int j = base + t; j < end; j += 256) {
    unsigned p = ebuf[j];
    int pos = atomicAdd(&cur[p >> 24], 1);
    csr[base + pos] = (int)(p & 0x00FFFFFFu);
  }
}

// ---------------- fp8 x16 unpack-accumulate (packed f32x2 adds) -------------
__device__ __forceinline__ void acc16p(f32x2* a, uint4 u) {
  a[0] += __builtin_amdgcn_cvt_pk_f32_fp8(u.x, false);
  a[1] += __builtin_amdgcn_cvt_pk_f32_fp8(u.x, true);
  a[2] += __builtin_amdgcn_cvt_pk_f32_fp8(u.y, false);
  a[3] += __builtin_amdgcn_cvt_pk_f32_fp8(u.y, true);
  a[4] += __builtin_amdgcn_cvt_pk_f32_fp8(u.z, false);
  a[5] += __builtin_amdgcn_cvt_pk_f32_fp8(u.z, true);
  a[6] += __builtin_amdgcn_cvt_pk_f32_fp8(u.w, false);
  a[7] += __builtin_amdgcn_cvt_pk_f32_fp8(u.w, true);
}

// ---------------- staging: fp32 row-major -> bf16 fragment-linear LDS -------
__device__ __forceinline__ void stage_f32(const float* __restrict__ X,
                                          int row0, int nvalid,
                                          uint4* buf, int t) {
#pragma unroll
  for (int i = 0; i < 8; i++) {
    int id = t + (i << 8);     // 0..2047
    int r = id >> 4;           // 0..127
    int c8 = id & 15;          // 0..15
    int row = row0 + r;
    float4 v0 = {0.f, 0.f, 0.f, 0.f}, v1 = {0.f, 0.f, 0.f, 0.f};
    if (row < nvalid) {
      const float4* p = (const float4*)(X + (size_t)row * DD + (c8 << 3));
      v0 = p[0];
      v1 = p[1];
    }
    uint4 q;
    q.x = f2bf2(v0.x, v0.y);
    q.y = f2bf2(v0.z, v0.w);
    q.z = f2bf2(v1.x, v1.y);
    q.w = f2bf2(v1.z, v1.w);
    int rt = r >> 4, m = r & 15, kc = c8 >> 2, quad = c8 & 3;
    buf[(((rt << 2) + kc) << 6) + (quad << 4) + m] = q;
  }
}

__device__ __forceinline__ void compute_half(const uint4* sA, const uint4* sW,
                                             f32x4 acc[2][8], int wv, int lane) {
#pragma unroll
  for (int kc = 0; kc < 4; kc++) {
    bf16x8 b[8];
#pragma unroll
    for (int n = 0; n < 8; n++)
      b[n] = *(const bf16x8*)&sW[(((n << 2) + kc) << 6) + lane];
    bf16x8 a0 = *(const bf16x8*)&sA[((((wv * 2 + 0) << 2) + kc) << 6) + lane];
    bf16x8 a1 = *(const bf16x8*)&sA[((((wv * 2 + 1) << 2) + kc) << 6) + lane];
#pragma unroll
    for (int n = 0; n < 8; n++) {
      acc[0][n] = __builtin_amdgcn_mfma_f32_16x16x32_bf16(a0, b[n], acc[0][n], 0, 0, 0);
      acc[1][n] = __builtin_amdgcn_mfma_f32_16x16x32_bf16(a1, b[n], acc[1][n], 0, 0, 0);
    }
  }
}

// ---------------- fused: gather-mean (fp8) -> LDS -> MFMA -> out ------------
// out = h@Ws^T + mean_{src in N(dst)}(h[src])@Wn^T + b
__global__ __launch_bounds__(256) void fused_gemm_kernel(
    const float* __restrict__ h, const uint4* __restrict__ h8,
    const int* __restrict__ offs, const int* __restrict__ csr,
    const float* __restrict__ Wself, const float* __restrict__ Wneigh,
    const float* __restrict__ bias, float* __restrict__ out) {
  __shared__ uint4 sA[2048];   // 32 KB A tile (fragment-linear bf16)
  __shared__ uint4 sW[2048];   // 32 KB W tile
  int t = threadIdx.x;
  int wv = t >> 6;
  int lane = t & 63;
  int row0 = blockIdx.x * 128;

  // stage Wneigh while gathering (no dependency on sA)
  stage_f32(Wneigh, 0, 128, sW, t);

  // ---- gather phase: 32 nodes per pass, 8 lanes/node, fp8 rows (128 B) ----
  int nsub = t >> 3;           // 0..31
  int l = t & 7;               // 16B chunk within row
#pragma unroll
  for (int p = 0; p < 4; p++) {
    int r = p * 32 + nsub;     // row within tile, 0..127
    int q = row0 + r;          // node id
    int off0 = 0, off1 = 0;
    if (q < NN) { off0 = offs[q]; off1 = offs[q + 1]; }
    f32x2 a[8];
#pragma unroll
    for (int i = 0; i < 8; i++) a[i] = f32x2{0.f, 0.f};
    int j = off0;
    for (; j + 4 <= off1; j += 4) {
      int s0 = csr[j], s1 = csr[j + 1], s2 = csr[j + 2], s3 = csr[j + 3];
      uint4 u0 = h8[(size_t)s0 * 8 + l];
      uint4 u1 = h8[(size_t)s1 * 8 + l];
      uint4 u2 = h8[(size_t)s2 * 8 + l];
      uint4 u3 = h8[(size_t)s3 * 8 + l];
      acc16p(a, u0); acc16p(a, u1); acc16p(a, u2); acc16p(a, u3);
    }
    for (; j < off1; j++) acc16p(a, h8[(size_t)csr[j] * 8 + l]);
    int deg = off1 - off0;
    float sc = (deg > 0) ? (1.0f / (float)deg) : 0.0f;
    uint4 r0, r1;
    r0.x = f2bf2(a[0].x * sc, a[0].y * sc);
    r0.y = f2bf2(a[1].x * sc, a[1].y * sc);
    r0.z = f2bf2(a[2].x * sc, a[2].y * sc);
    r0.w = f2bf2(a[3].x * sc, a[3].y * sc);
    r1.x = f2bf2(a[4].x * sc, a[4].y * sc);
    r1.y = f2bf2(a[5].x * sc, a[5].y * sc);
    r1.z = f2bf2(a[6].x * sc, a[6].y * sc);
    r1.w = f2bf2(a[7].x * sc, a[7].y * sc);
    // write into fragment-linear sA: row r, col-octets c8 = 2l, 2l+1
    int rt = r >> 4, m = r & 15;
    int c80 = 2 * l, c81 = 2 * l + 1;
    sA[(((rt << 2) + (c80 >> 2)) << 6) + ((c80 & 3) << 4) + m] = r0;
    sA[(((rt << 2) + (c81 >> 2)) << 6) + ((c81 & 3) << 4) + m] = r1;
  }
  __syncthreads();

  f32x4 acc[2][8];
#pragma unroll
  for (int i = 0; i < 2; i++)
#pragma unroll
    for (int n = 0; n < 8; n++) acc[i][n] = f32x4{0.f, 0.f, 0.f, 0.f};

  // neighbor half: hneigh(tile, in LDS) @ Wneigh^T
  compute_half(sA, sW, acc, wv, lane);
  __syncthreads();

  // self half: h @ Wself^T
  stage_f32(h, row0, NN, sA, t);
  stage_f32(Wself, 0, 128, sW, t);
  __syncthreads();
  compute_half(sA, sW, acc, wv, lane);

  // epilogue: + bias (C/D layout: col=lane&15, row=(lane>>4)*4+reg)
  int col = lane & 15, rq = lane >> 4;
  float bv[8];
#pragma unroll
  for (int n = 0; n < 8; n++) bv[n] = bias[n * 16 + col];
#pragma unroll
  for (int rt = 0; rt < 2; rt++) {
    int rb = row0 + (wv * 2 + rt) * 16 + rq * 4;
#pragma unroll
    for (int r = 0; r < 4; r++) {
      int row = rb + r;
      if (row < NN) {
        float* op = out + (size_t)row * DD + col;
#pragma unroll
        for (int n = 0; n < 8; n++) op[n * 16] = acc[rt][n][r] + bv[n];
      }
    }
  }
}

extern "C" void kernel_launch(void* const* d_in, const int* in_sizes, int n_in,
                              void* d_out, int out_size, void* d_ws, size_t ws_size,
                              hipStream_t stream) {
  const float* h      = (const float*)d_in[0];
  const int*   src    = (const int*)d_in[1];
  const int*   dst    = (const int*)d_in[2];
  const float* Wself  = (const float*)d_in[3];
  const float* Wneigh = (const float*)d_in[4];
  const float* bias   = (const float*)d_in[5];
  float* out = (float*)d_out;

  // workspace layout (bytes); peak footprint ~27.2 MB
  char* ws = (char*)d_ws;
  unsigned* h8       = (unsigned*)ws;                     // 12,800,000
  unsigned* ebuf     = (unsigned*)(ws + 12800000);        //  6,400,000
  int*      csr      = (int*)(ws + 19200000);             //  6,400,000
  int*      gh       = (int*)(ws + 25600000);             //    400,384
  int*      gsc      = (int*)(ws + 26000384);             //    400,384
  int*      bsum     = (int*)(ws + 26400768);             //      1,568
  int*      bsum_ex  = (int*)(ws + 26402336);             //      1,568
  int*      offs     = (int*)(ws + 26403904);             //    400,016

  convert_h8_kernel<<<6250, 256, 0, stream>>>((const float4*)h, (uint2*)h8);
  coarse_hist_kernel<<<NB, 256, 0, stream>>>(dst, gh);
  blocksum_kernel<<<GH_BLK, 256, 0, stream>>>(gh, bsum);
  scanbsum_kernel<<<1, 512, 0, stream>>>(bsum, bsum_ex);
  scanfull_kernel<<<GH_BLK, 256, 0, stream>>>(gh, bsum_ex, gsc);
  coarse_scatter_kernel<<<NB, 256, 0, stream>>>(src, dst, gsc, ebuf);
  fine_sort_kernel<<<NBUCK, 256, 0, stream>>>(ebuf, gsc, csr, offs);
  fused_gemm_kernel<<<NTILES, 256, 0, stream>>>(h, (const uint4*)h8, offs, csr,
                                                Wself, Wneigh, bias, out);
}